// Round 1
// baseline (926.328 us; speedup 1.0000x reference)
//
#include <hip/hip_runtime.h>
#include <hip/hip_bf16.h>
#include <math.h>

#define N_NODES 32000
#define NUM_GRAPHS 32
#define NPG 1000
#define N_EDGES 256000
#define IN_DIM 1024
#define HID 256
#define CLU 8

// ---------------- zero fill ----------------
__global__ void fill_zero_u32(unsigned int* __restrict__ p, int n) {
  int i = blockIdx.x * blockDim.x + threadIdx.x;
  if (i < n) p[i] = 0u;
}

// ---------------- main GEMM: C[32000,512] = x @ [Wl1 | Wr1] ----------------
// BM=128, BN=128, BK=16, 256 threads, 8x8 micro-tile per thread.
// Wave maps to an 8x8 lane grid so LDS fragment reads are max 2-way conflicts (free).
__global__ __launch_bounds__(256) void gemm512(
    const float* __restrict__ x, const float* __restrict__ Wl1,
    const float* __restrict__ Wr1, float* __restrict__ C)
{
  const int m0 = blockIdx.x * 128;
  const int nb = blockIdx.y;  // 0..3 -> cols [0:128) of Wl1, [128:256) of Wl1, [0:128) Wr1, [128:256) Wr1
  const float* W = (nb < 2) ? (Wl1 + nb * 128) : (Wr1 + (nb - 2) * 128);
  __shared__ float As[16][128];  // [k][m] transposed A tile
  __shared__ float Bs[16][128];  // [k][n]
  const int tid = threadIdx.x;
  // staging indices
  const int arow  = tid >> 1;          // 0..127
  const int akseg = (tid & 1) << 3;    // 0 or 8
  const int bk    = tid >> 4;          // 0..15
  const int bcol  = (tid & 15) << 3;   // 0..120
  // compute indices: 4 waves in 2x2, 64 lanes in 8x8
  const int w = tid >> 6, l = tid & 63;
  const int rowBase = ((w >> 1) << 6) + ((l >> 3) << 3);
  const int colBase = ((w & 1) << 6) + ((l & 7) << 3);

  float acc[8][8];
#pragma unroll
  for (int i = 0; i < 8; ++i)
#pragma unroll
    for (int j = 0; j < 8; ++j) acc[i][j] = 0.f;

  const float* xrow = x + (size_t)(m0 + arow) * IN_DIM + akseg;
  const float* wrow = W + (size_t)bk * HID + bcol;

  for (int k0 = 0; k0 < IN_DIM; k0 += 16) {
    float4 a0 = *(const float4*)(xrow + k0);
    float4 a1 = *(const float4*)(xrow + k0 + 4);
    float4 b0 = *(const float4*)(wrow + (size_t)k0 * HID);
    float4 b1 = *(const float4*)(wrow + (size_t)k0 * HID + 4);
    __syncthreads();
    As[akseg + 0][arow] = a0.x;  As[akseg + 1][arow] = a0.y;
    As[akseg + 2][arow] = a0.z;  As[akseg + 3][arow] = a0.w;
    As[akseg + 4][arow] = a1.x;  As[akseg + 5][arow] = a1.y;
    As[akseg + 6][arow] = a1.z;  As[akseg + 7][arow] = a1.w;
    *(float4*)&Bs[bk][bcol]     = b0;
    *(float4*)&Bs[bk][bcol + 4] = b1;
    __syncthreads();
#pragma unroll
    for (int k = 0; k < 16; ++k) {
      float a[8], b[8];
      *(float4*)&a[0] = *(const float4*)&As[k][rowBase];
      *(float4*)&a[4] = *(const float4*)&As[k][rowBase + 4];
      *(float4*)&b[0] = *(const float4*)&Bs[k][colBase];
      *(float4*)&b[4] = *(const float4*)&Bs[k][colBase + 4];
#pragma unroll
      for (int i = 0; i < 8; ++i)
#pragma unroll
        for (int j = 0; j < 8; ++j)
          acc[i][j] = fmaf(a[i], b[j], acc[i][j]);
    }
  }
  const int ccol = nb * 128 + colBase;
#pragma unroll
  for (int i = 0; i < 8; ++i) {
    float* crow = C + (size_t)(m0 + rowBase + i) * 512 + ccol;
    *(float4*)crow       = make_float4(acc[i][0], acc[i][1], acc[i][2], acc[i][3]);
    *(float4*)(crow + 4) = make_float4(acc[i][4], acc[i][5], acc[i][6], acc[i][7]);
  }
}

// ---------------- skinny GEMM: SP[32000,16] = x @ [Wla | Wra] ----------------
// One wave per 2 rows; lane covers K with stride 64; shuffle-reduce.
__global__ __launch_bounds__(256) void skinny16(
    const float* __restrict__ x, const float* __restrict__ Wla,
    const float* __restrict__ Wra, float* __restrict__ SP)
{
  const int wid  = (blockIdx.x << 2) + (threadIdx.x >> 6);
  const int lane = threadIdx.x & 63;
  const int r0 = wid * 2, r1 = r0 + 1;
  float acc[32];
#pragma unroll
  for (int i = 0; i < 32; ++i) acc[i] = 0.f;
  const float* x0 = x + (size_t)r0 * IN_DIM;
  const float* x1 = x + (size_t)r1 * IN_DIM;
#pragma unroll 2
  for (int j = 0; j < 16; ++j) {
    int k = (j << 6) + lane;
    float wv[16];
    *(float4*)&wv[0]  = *(const float4*)(Wla + (size_t)k * 8);
    *(float4*)&wv[4]  = *(const float4*)(Wla + (size_t)k * 8 + 4);
    *(float4*)&wv[8]  = *(const float4*)(Wra + (size_t)k * 8);
    *(float4*)&wv[12] = *(const float4*)(Wra + (size_t)k * 8 + 4);
    float xv0 = x0[k], xv1 = x1[k];
#pragma unroll
    for (int c = 0; c < 16; ++c) {
      acc[c]      = fmaf(xv0, wv[c], acc[c]);
      acc[16 + c] = fmaf(xv1, wv[c], acc[16 + c]);
    }
  }
#pragma unroll
  for (int i = 0; i < 32; ++i) {
    acc[i] += __shfl_xor(acc[i], 32);
    acc[i] += __shfl_xor(acc[i], 16);
    acc[i] += __shfl_xor(acc[i], 8);
    acc[i] += __shfl_xor(acc[i], 4);
    acc[i] += __shfl_xor(acc[i], 2);
    acc[i] += __shfl_xor(acc[i], 1);
  }
  if (lane == 0) {
    float4* o0 = (float4*)(SP + (size_t)r0 * 16);
    o0[0] = make_float4(acc[0], acc[1], acc[2], acc[3]);
    o0[1] = make_float4(acc[4], acc[5], acc[6], acc[7]);
    o0[2] = make_float4(acc[8], acc[9], acc[10], acc[11]);
    o0[3] = make_float4(acc[12], acc[13], acc[14], acc[15]);
    float4* o1 = (float4*)(SP + (size_t)r1 * 16);
    o1[0] = make_float4(acc[16], acc[17], acc[18], acc[19]);
    o1[1] = make_float4(acc[20], acc[21], acc[22], acc[23]);
    o1[2] = make_float4(acc[24], acc[25], acc[26], acc[27]);
    o1[3] = make_float4(acc[28], acc[29], acc[30], acc[31]);
  }
}

// ---------------- CSR build ----------------
__global__ void count_deg(const int* __restrict__ dst, int* __restrict__ deg) {
  int e = blockIdx.x * blockDim.x + threadIdx.x;
  if (e < N_EDGES) atomicAdd(&deg[dst[e]], 1);
}

__global__ __launch_bounds__(1024) void scan_kernel(const int* __restrict__ deg,
                                                    int* __restrict__ offsets) {
  __shared__ int part[1024];
  const int t = threadIdx.x;
  const int base = t * 32;
  int local[32];
  int s = 0;
#pragma unroll
  for (int i = 0; i < 32; ++i) {
    int idx = base + i;
    int v = (idx < N_NODES) ? deg[idx] : 0;
    local[i] = s;
    s += v;
  }
  part[t] = s;
  __syncthreads();
  for (int off = 1; off < 1024; off <<= 1) {
    int v = (t >= off) ? part[t - off] : 0;
    __syncthreads();
    part[t] += v;
    __syncthreads();
  }
  int excl = part[t] - s;
#pragma unroll
  for (int i = 0; i < 32; ++i) {
    int idx = base + i;
    if (idx < N_NODES) offsets[idx] = excl + local[i];
  }
  if (t == 1023) offsets[N_NODES] = part[1023];
}

__global__ void scatter_kernel(const int* __restrict__ src, const int* __restrict__ dst,
                               const int* __restrict__ offsets, int* __restrict__ cursor,
                               int* __restrict__ srcSorted) {
  int e = blockIdx.x * blockDim.x + threadIdx.x;
  if (e < N_EDGES) {
    int d = dst[e];
    int pos = offsets[d] + atomicAdd(&cursor[d], 1);
    srcSorted[pos] = src[e];
  }
}

// ---------------- per-node aggregation: Z = relu(mean(P1)+bl1+R1), Ss = softmax(mean(Pa)+bla+Ra) ----------------
__global__ __launch_bounds__(256) void aggregate_node(
    const float* __restrict__ C, const float* __restrict__ SP,
    const int* __restrict__ offsets, const int* __restrict__ srcSorted,
    const float* __restrict__ bl1, const float* __restrict__ bla,
    float* __restrict__ Z, float* __restrict__ Ss)
{
  const int node = blockIdx.x;
  const int t = threadIdx.x;
  const int b = offsets[node], e = offsets[node + 1];
  const int cnt = e - b;
  float accP = 0.f;
  for (int p = b; p < e; ++p) {
    int s = srcSorted[p];
    accP += C[(size_t)s * 512 + t];
  }
  float mean = (cnt > 0) ? accP / (float)cnt : 0.f;
  float z = mean + bl1[t] + C[(size_t)node * 512 + 256 + t];
  Z[(size_t)node * 256 + t] = fmaxf(z, 0.f);

  __shared__ float sS[8];
  if (t < 8) {
    float a = 0.f;
    for (int p = b; p < e; ++p) a += SP[(size_t)srcSorted[p] * 16 + t];
    float sv = ((cnt > 0) ? a / (float)cnt : 0.f) + bla[t] + SP[(size_t)node * 16 + 8 + t];
    sS[t] = sv;
  }
  __syncthreads();
  if (t < 8) {
    float m = sS[0];
#pragma unroll
    for (int c = 1; c < 8; ++c) m = fmaxf(m, sS[c]);
    float denom = 0.f;
#pragma unroll
    for (int c = 0; c < 8; ++c) denom += expf(sS[c] - m);
    Ss[(size_t)node * 8 + t] = expf(sS[t] - m) / denom;
  }
}

// ---------------- AggS[node,i] = sum_{s in N(node)} Ss[s,i] ----------------
__global__ __launch_bounds__(256) void agg_ss(
    const float* __restrict__ Ss, const int* __restrict__ offsets,
    const int* __restrict__ srcSorted, float* __restrict__ AggS)
{
  int idx = blockIdx.x * 256 + threadIdx.x;  // 32 nodes x 8 channels per block
  int node = idx >> 3, c = idx & 7;
  if (node >= N_NODES) return;
  int b = offsets[node], e = offsets[node + 1];
  float s = 0.f;
  for (int p = b; p < e; ++p) s += Ss[(size_t)srcSorted[p] * 8 + c];
  AggS[idx] = s;
}

// ---------------- Xp[g,c,h] = sum_{n in g} Ss[n,c] * Z[n,h]  (8 chunks/graph, atomic flush) ----------------
__global__ __launch_bounds__(256) void xp_kernel(
    const float* __restrict__ Ss, const float* __restrict__ Z,
    float* __restrict__ Xp)
{
  const int g = blockIdx.x >> 3;
  const int chunk = blockIdx.x & 7;
  const int t = threadIdx.x;
  const int n0 = g * NPG + chunk * 125;
  __shared__ float ls[32 * 8];
  float acc[8];
#pragma unroll
  for (int c = 0; c < 8; ++c) acc[c] = 0.f;
  for (int c0 = 0; c0 < 125; c0 += 32) {
    int cc = min(32, 125 - c0);
    __syncthreads();
    if (t < cc * 8) ls[t] = Ss[(size_t)(n0 + c0) * 8 + t];
    __syncthreads();
    for (int i = 0; i < cc; ++i) {
      float zv = Z[(size_t)(n0 + c0 + i) * 256 + t];
#pragma unroll
      for (int c = 0; c < 8; ++c) acc[c] = fmaf(ls[i * 8 + c], zv, acc[c]);
    }
  }
#pragma unroll
  for (int c = 0; c < 8; ++c)
    atomicAdd(&Xp[((size_t)g * 8 + c) * 256 + t], acc[c]);
}

// ---------------- Ap[g,i,j] = sum_{n in g} AggS[n,i] * Ss[n,j] ----------------
__global__ __launch_bounds__(64) void ap_kernel(
    const float* __restrict__ AggS, const float* __restrict__ Ss,
    float* __restrict__ Ap)
{
  const int g = blockIdx.x;
  const int t = threadIdx.x;  // 64 threads = 8x8
  const int i = t >> 3, j = t & 7;
  __shared__ float lA[64 * 8], lS[64 * 8];
  float acc = 0.f;
  const int base = g * NPG;
  for (int c0 = 0; c0 < NPG; c0 += 64) {
    int cc = min(64, NPG - c0);
    __syncthreads();
    if (t < cc) {
      const float4* pa = (const float4*)(AggS + (size_t)(base + c0 + t) * 8);
      *(float4*)&lA[t * 8]     = pa[0];
      *(float4*)&lA[t * 8 + 4] = pa[1];
      const float4* ps = (const float4*)(Ss + (size_t)(base + c0 + t) * 8);
      *(float4*)&lS[t * 8]     = ps[0];
      *(float4*)&lS[t * 8 + 4] = ps[1];
    }
    __syncthreads();
    for (int n = 0; n < cc; ++n) acc = fmaf(lA[n * 8 + i], lS[n * 8 + j], acc);
  }
  Ap[(size_t)g * 64 + t] = acc;
}

// ---------------- final: mask/deg -> agg -> Zp -> classifier -> out[g] ----------------
__global__ __launch_bounds__(256) void final_kernel(
    const float* __restrict__ Xp, const float* __restrict__ Ap,
    const float* __restrict__ Wl2, const float* __restrict__ bl2,
    const float* __restrict__ Wr2, const float* __restrict__ Wc1,
    const float* __restrict__ bc1, const float* __restrict__ Wc2,
    const float* __restrict__ bc2, float* __restrict__ out)
{
  const int g = blockIdx.x;
  const int t = threadIdx.x;
  __shared__ float lAp[64];
  __shared__ float lXp[8][256];
  __shared__ float lAgg[8][256];
  __shared__ float lG[2048];
  __shared__ float red[256];
  if (t < 64) lAp[t] = Ap[g * 64 + t];
#pragma unroll
  for (int i = 0; i < 8; ++i) lXp[i][t] = Xp[((size_t)g * 8 + i) * 256 + t];
  __syncthreads();
#pragma unroll
  for (int j = 0; j < 8; ++j) {
    float d = 0.f, s = 0.f;
#pragma unroll
    for (int i = 0; i < 8; ++i) {
      bool m = (lAp[i * 8 + j] != 0.f);
      d += m ? 1.f : 0.f;
      s += m ? lXp[i][t] : 0.f;
    }
    lAgg[j][t] = (d > 0.f) ? s / fmaxf(d, 1.f) : 0.f;
  }
  __syncthreads();
  // Zp[j][t] = relu(bl2 + sum_k lAgg[j][k]*Wl2[k][t] + lXp[j][k]*Wr2[k][t])
  float az[8];
#pragma unroll
  for (int j = 0; j < 8; ++j) az[j] = bl2[t];
#pragma unroll 4
  for (int k = 0; k < 256; ++k) {
    float wl = Wl2[(size_t)k * 256 + t];
    float wr = Wr2[(size_t)k * 256 + t];
#pragma unroll
    for (int j = 0; j < 8; ++j)
      az[j] += lAgg[j][k] * wl + lXp[j][k] * wr;
  }
#pragma unroll
  for (int j = 0; j < 8; ++j) lG[j * 256 + t] = fmaxf(az[j], 0.f);
  __syncthreads();
  float a = bc1[t];
#pragma unroll 4
  for (int k = 0; k < 2048; ++k) a = fmaf(lG[k], Wc1[(size_t)k * 256 + t], a);
  float h2 = fmaxf(a, 0.f);
  red[t] = h2 * Wc2[t];
  __syncthreads();
  for (int off = 128; off > 0; off >>= 1) {
    if (t < off) red[t] += red[t + off];
    __syncthreads();
  }
  if (t == 0) out[g] = red[0] + bc2[0];
}

extern "C" void kernel_launch(void* const* d_in, const int* in_sizes, int n_in,
                              void* d_out, int out_size, void* d_ws, size_t ws_size,
                              hipStream_t stream) {
  const float* x   = (const float*)d_in[0];
  const int*   ei  = (const int*)d_in[1];
  // d_in[2] = batch (unused: nodes are contiguous per graph)
  const float* Wl1 = (const float*)d_in[3];
  const float* bl1 = (const float*)d_in[4];
  const float* Wr1 = (const float*)d_in[5];
  const float* Wla = (const float*)d_in[6];
  const float* bla = (const float*)d_in[7];
  const float* Wra = (const float*)d_in[8];
  const float* Wl2 = (const float*)d_in[9];
  const float* bl2 = (const float*)d_in[10];
  const float* Wr2 = (const float*)d_in[11];
  const float* Wc1 = (const float*)d_in[12];
  const float* bc1 = (const float*)d_in[13];
  const float* Wc2 = (const float*)d_in[14];
  const float* bc2 = (const float*)d_in[15];
  float* out = (float*)d_out;

  // workspace layout (~100 MB)
  float* C    = (float*)d_ws;           // 32000*512
  float* SP   = C + 16384000;           // 32000*16
  float* Z    = SP + 512000;            // 32000*256
  float* Ss   = Z + 8192000;            // 32000*8
  float* AggS = Ss + 256000;            // 32000*8
  float* Xp   = AggS + 256000;          // 32*8*256
  float* Ap   = Xp + 65536;             // 32*64
  int* deg     = (int*)(Ap + 2048);     // 32000
  int* cursor  = deg + 32000;           // 32000
  int* offsets = cursor + 32000;        // 32001
  int* srcS    = offsets + 32001;       // 256000

  const int* src = ei;
  const int* dst = ei + N_EDGES;

  fill_zero_u32<<<(64000 + 255) / 256, 256, 0, stream>>>((unsigned*)deg, 64000);
  fill_zero_u32<<<(65536 + 255) / 256, 256, 0, stream>>>((unsigned*)Xp, 65536);

  gemm512<<<dim3(250, 4), 256, 0, stream>>>(x, Wl1, Wr1, C);
  skinny16<<<4000, 256, 0, stream>>>(x, Wla, Wra, SP);

  count_deg<<<1000, 256, 0, stream>>>(dst, deg);
  scan_kernel<<<1, 1024, 0, stream>>>(deg, offsets);
  scatter_kernel<<<1000, 256, 0, stream>>>(src, dst, offsets, cursor, srcS);

  aggregate_node<<<32000, 256, 0, stream>>>(C, SP, offsets, srcS, bl1, bla, Z, Ss);
  agg_ss<<<1000, 256, 0, stream>>>(Ss, offsets, srcS, AggS);
  xp_kernel<<<256, 256, 0, stream>>>(Ss, Z, Xp);
  ap_kernel<<<32, 64, 0, stream>>>(AggS, Ss, Ap);
  final_kernel<<<32, 256, 0, stream>>>(Xp, Ap, Wl2, bl2, Wr2, Wc1, bc1, Wc2, bc2, out);
}

// Round 2
// 464.672 us; speedup vs baseline: 1.9935x; 1.9935x over previous
//
#include <hip/hip_runtime.h>
#include <hip/hip_bf16.h>
#include <math.h>

#define N_NODES 32000
#define NUM_GRAPHS 32
#define NPG 1000
#define N_EDGES 256000
#define IN_DIM 1024
#define HID 256
#define CLU 8

typedef _Float16 half8 __attribute__((ext_vector_type(8)));
typedef _Float16 half4v __attribute__((ext_vector_type(4)));
typedef float f32x4 __attribute__((ext_vector_type(4)));

__device__ __forceinline__ void gload16(const void* g, void* l) {
  __builtin_amdgcn_global_load_lds((const __attribute__((address_space(1))) void*)g,
                                   (__attribute__((address_space(3))) void*)l, 16, 0, 0);
}

// ---------------- zero fill ----------------
__global__ void fill_zero_u32(unsigned int* __restrict__ p, int n) {
  int i = blockIdx.x * blockDim.x + threadIdx.x;
  if (i < n) p[i] = 0u;
}

// ---------------- W transpose+convert: WsT[512][1024] fp16, WsT[n][k] = fp16(W[k][n]) ----------------
// W = [Wl1 | Wr1] column-concat (n<256 -> Wl1, else Wr1).
__global__ __launch_bounds__(256) void convert_w(
    const float* __restrict__ Wl1, const float* __restrict__ Wr1,
    _Float16* __restrict__ WsT)
{
  const int kb = blockIdx.x * 32;
  const int nb = blockIdx.y * 32;
  __shared__ float ls[32][33];
  const int t = threadIdx.x;
  {
    const int r = t >> 3, c4 = (t & 7) << 2;
    const int n = nb + c4;
    const float* Wsrc = (n < 256) ? (Wl1 + n) : (Wr1 + n - 256);
    float4 v = *(const float4*)(Wsrc + (size_t)(kb + r) * 256);
    ls[r][c4 + 0] = v.x; ls[r][c4 + 1] = v.y; ls[r][c4 + 2] = v.z; ls[r][c4 + 3] = v.w;
  }
  __syncthreads();
  {
    const int wn = t >> 3, wk4 = (t & 7) << 2;
    half4v o;
    o[0] = (_Float16)ls[wk4 + 0][wn];
    o[1] = (_Float16)ls[wk4 + 1][wn];
    o[2] = (_Float16)ls[wk4 + 2][wn];
    o[3] = (_Float16)ls[wk4 + 3][wn];
    *(half4v*)&WsT[(size_t)(nb + wn) * 1024 + kb + wk4] = o;
  }
}

// ---------------- MFMA GEMM: C[32000,512](fp16) = x @ [Wl1|Wr1] via split-fp16 ----------------
// BM=128, BN=128, BK=32 (orig K), 4 waves, per-wave 64x64 = 4x4 frags of 16x16.
// Per K-step: A f32 tile -> cvt hi/lo fp16 -> LDS; B fp16 via global_load_lds.
// acc += mfma(A_hi,B) + mfma(A_lo,B)  (2-term split: error ~1e-4, threshold 0.6).
__global__ __launch_bounds__(256) void gemm_mfma(
    const float* __restrict__ x, const _Float16* __restrict__ WsT,
    _Float16* __restrict__ C)
{
  const int bid = blockIdx.x;
  const int g = (bid & 7) * 125 + (bid >> 3);   // XCD-contiguous mapping
  const int pm = g >> 2, nb = g & 3;
  const int m0 = pm * 128, n0 = nb * 128;

  __shared__ _Float16 AsH[128][32];
  __shared__ _Float16 AsL[128][32];
  __shared__ _Float16 Bs[128][32];   // [n][k] (pre-transposed global layout)

  const int tid = threadIdx.x;
  const int w = tid >> 6, l = tid & 63;
  const int wr = w >> 1, wc = w & 1;
  const int r16 = l & 15, ks = (l >> 4) << 3;

  // A staging: thread -> row tid>>1, k-offset (tid&1)*16 (16 f32 each)
  const int arow = tid >> 1, akc = (tid & 1) << 4;
  const float* aptr = x + (size_t)(m0 + arow) * IN_DIM + akc;
  // B staging: 512 x 16B chunks; chunk i: n=i>>2, kc=(i&3)*8
  const _Float16* bptr0 = WsT + (size_t)(n0 + (tid >> 2)) * 1024 + ((tid & 3) << 3);
  const _Float16* bptr1 = WsT + (size_t)(n0 + ((tid + 256) >> 2)) * 1024 + (((tid + 256) & 3) << 3);
  _Float16* bl0 = &Bs[0][0] + tid * 8;
  _Float16* bl1 = &Bs[0][0] + (tid + 256) * 8;

  f32x4 acc[4][4] = {};

  for (int k0 = 0; k0 < IN_DIM; k0 += 32) {
    float av[16];
    *(float4*)&av[0]  = *(const float4*)(aptr + k0);
    *(float4*)&av[4]  = *(const float4*)(aptr + k0 + 4);
    *(float4*)&av[8]  = *(const float4*)(aptr + k0 + 8);
    *(float4*)&av[12] = *(const float4*)(aptr + k0 + 12);
    __syncthreads();                       // previous compute done with LDS
    gload16(bptr0 + k0, bl0);              // async B -> LDS
    gload16(bptr1 + k0, bl1);
    half8 hh[2], hl[2];
#pragma unroll
    for (int i = 0; i < 16; ++i) {
      _Float16 h = (_Float16)av[i];
      ((_Float16*)hh)[i] = h;
      ((_Float16*)hl)[i] = (_Float16)(av[i] - (float)h);
    }
    *(half8*)&AsH[arow][akc]     = hh[0];
    *(half8*)&AsH[arow][akc + 8] = hh[1];
    *(half8*)&AsL[arow][akc]     = hl[0];
    *(half8*)&AsL[arow][akc + 8] = hl[1];
    __syncthreads();                       // drains vmcnt (gload) + lgkm (ds_write)

    half8 bf[4];
#pragma unroll
    for (int n = 0; n < 4; ++n) bf[n] = *(half8*)&Bs[wc * 64 + n * 16 + r16][ks];
#pragma unroll
    for (int m = 0; m < 4; ++m) {
      half8 ah = *(half8*)&AsH[wr * 64 + m * 16 + r16][ks];
      half8 al = *(half8*)&AsL[wr * 64 + m * 16 + r16][ks];
#pragma unroll
      for (int n = 0; n < 4; ++n) {
        acc[m][n] = __builtin_amdgcn_mfma_f32_16x16x32_f16(ah, bf[n], acc[m][n], 0, 0, 0);
        acc[m][n] = __builtin_amdgcn_mfma_f32_16x16x32_f16(al, bf[n], acc[m][n], 0, 0, 0);
      }
    }
  }
  // C/D layout: col = lane&15, row = (lane>>4)*4 + reg
  const int crow0 = m0 + wr * 64 + (l >> 4) * 4;
  const int ccol0 = n0 + wc * 64 + r16;
#pragma unroll
  for (int m = 0; m < 4; ++m)
#pragma unroll
    for (int n = 0; n < 4; ++n)
#pragma unroll
      for (int r = 0; r < 4; ++r)
        C[(size_t)(crow0 + m * 16 + r) * 512 + ccol0 + n * 16] = (_Float16)acc[m][n][r];
}

// ---------------- skinny GEMM: SP[32000,16] = x @ [Wla | Wra] ----------------
__global__ __launch_bounds__(256) void skinny16(
    const float* __restrict__ x, const float* __restrict__ Wla,
    const float* __restrict__ Wra, float* __restrict__ SP)
{
  const int wid  = (blockIdx.x << 2) + (threadIdx.x >> 6);
  const int lane = threadIdx.x & 63;
  const int r0 = wid * 2, r1 = r0 + 1;
  float acc[32];
#pragma unroll
  for (int i = 0; i < 32; ++i) acc[i] = 0.f;
  const float* x0 = x + (size_t)r0 * IN_DIM;
  const float* x1 = x + (size_t)r1 * IN_DIM;
#pragma unroll 2
  for (int j = 0; j < 16; ++j) {
    int k = (j << 6) + lane;
    float wv[16];
    *(float4*)&wv[0]  = *(const float4*)(Wla + (size_t)k * 8);
    *(float4*)&wv[4]  = *(const float4*)(Wla + (size_t)k * 8 + 4);
    *(float4*)&wv[8]  = *(const float4*)(Wra + (size_t)k * 8);
    *(float4*)&wv[12] = *(const float4*)(Wra + (size_t)k * 8 + 4);
    float xv0 = x0[k], xv1 = x1[k];
#pragma unroll
    for (int c = 0; c < 16; ++c) {
      acc[c]      = fmaf(xv0, wv[c], acc[c]);
      acc[16 + c] = fmaf(xv1, wv[c], acc[16 + c]);
    }
  }
#pragma unroll
  for (int i = 0; i < 32; ++i) {
    acc[i] += __shfl_xor(acc[i], 32);
    acc[i] += __shfl_xor(acc[i], 16);
    acc[i] += __shfl_xor(acc[i], 8);
    acc[i] += __shfl_xor(acc[i], 4);
    acc[i] += __shfl_xor(acc[i], 2);
    acc[i] += __shfl_xor(acc[i], 1);
  }
  if (lane == 0) {
    float4* o0 = (float4*)(SP + (size_t)r0 * 16);
    o0[0] = make_float4(acc[0], acc[1], acc[2], acc[3]);
    o0[1] = make_float4(acc[4], acc[5], acc[6], acc[7]);
    o0[2] = make_float4(acc[8], acc[9], acc[10], acc[11]);
    o0[3] = make_float4(acc[12], acc[13], acc[14], acc[15]);
    float4* o1 = (float4*)(SP + (size_t)r1 * 16);
    o1[0] = make_float4(acc[16], acc[17], acc[18], acc[19]);
    o1[1] = make_float4(acc[20], acc[21], acc[22], acc[23]);
    o1[2] = make_float4(acc[24], acc[25], acc[26], acc[27]);
    o1[3] = make_float4(acc[28], acc[29], acc[30], acc[31]);
  }
}

// ---------------- CSR build ----------------
__global__ void count_deg(const int* __restrict__ dst, int* __restrict__ deg) {
  int e = blockIdx.x * blockDim.x + threadIdx.x;
  if (e < N_EDGES) atomicAdd(&deg[dst[e]], 1);
}

__global__ __launch_bounds__(1024) void scan_kernel(const int* __restrict__ deg,
                                                    int* __restrict__ offsets) {
  __shared__ int part[1024];
  const int t = threadIdx.x;
  const int base = t * 32;
  int vals[32];
  if (t < 1000) {
#pragma unroll
    for (int j = 0; j < 8; ++j) {
      int4 v = *(const int4*)(deg + base + j * 4);
      vals[j * 4 + 0] = v.x; vals[j * 4 + 1] = v.y;
      vals[j * 4 + 2] = v.z; vals[j * 4 + 3] = v.w;
    }
  } else {
#pragma unroll
    for (int i = 0; i < 32; ++i) vals[i] = 0;
  }
  int local[32];
  int s = 0;
#pragma unroll
  for (int i = 0; i < 32; ++i) { local[i] = s; s += vals[i]; }
  part[t] = s;
  __syncthreads();
  for (int off = 1; off < 1024; off <<= 1) {
    int v = (t >= off) ? part[t - off] : 0;
    __syncthreads();
    part[t] += v;
    __syncthreads();
  }
  int excl = part[t] - s;
  if (t < 1000) {
#pragma unroll
    for (int i = 0; i < 32; ++i) offsets[base + i] = excl + local[i];
  }
  if (t == 1023) offsets[N_NODES] = part[1023];
}

__global__ void scatter_kernel(const int* __restrict__ src, const int* __restrict__ dst,
                               const int* __restrict__ offsets, int* __restrict__ cursor,
                               int* __restrict__ srcSorted) {
  int e = blockIdx.x * blockDim.x + threadIdx.x;
  if (e < N_EDGES) {
    int d = dst[e];
    int pos = offsets[d] + atomicAdd(&cursor[d], 1);
    srcSorted[pos] = src[e];
  }
}

// ---------------- per-node aggregation ----------------
// Z = relu(mean(Cl)+bl1+Cr), Ss = softmax(mean(SPa)+bla+SPr). C is fp16 [32000][512].
__global__ __launch_bounds__(256) void aggregate_node(
    const _Float16* __restrict__ C, const float* __restrict__ SP,
    const int* __restrict__ offsets, const int* __restrict__ srcSorted,
    const float* __restrict__ bl1, const float* __restrict__ bla,
    float* __restrict__ Z, float* __restrict__ Ss)
{
  const int bid = blockIdx.x;
  const int node = (bid & 7) * 4000 + (bid >> 3);   // graph-contiguous per XCD
  const int t = threadIdx.x;
  const int b = offsets[node], e = offsets[node + 1];
  const int cnt = e - b;
  float accP = 0.f;
  for (int p = b; p < e; ++p) {
    int s = srcSorted[p];
    accP += (float)C[(size_t)s * 512 + t];
  }
  float mean = (cnt > 0) ? accP / (float)cnt : 0.f;
  float z = mean + bl1[t] + (float)C[(size_t)node * 512 + 256 + t];
  Z[(size_t)node * 256 + t] = fmaxf(z, 0.f);

  __shared__ float sS[8];
  if (t < 8) {
    float a = 0.f;
    for (int p = b; p < e; ++p) a += SP[(size_t)srcSorted[p] * 16 + t];
    float sv = ((cnt > 0) ? a / (float)cnt : 0.f) + bla[t] + SP[(size_t)node * 16 + 8 + t];
    sS[t] = sv;
  }
  __syncthreads();
  if (t < 8) {
    float m = sS[0];
#pragma unroll
    for (int c = 1; c < 8; ++c) m = fmaxf(m, sS[c]);
    float denom = 0.f;
#pragma unroll
    for (int c = 0; c < 8; ++c) denom += expf(sS[c] - m);
    Ss[(size_t)node * 8 + t] = expf(sS[t] - m) / denom;
  }
}

// ---------------- AggS[node,i] = sum_{s in N(node)} Ss[s,i] ----------------
__global__ __launch_bounds__(256) void agg_ss(
    const float* __restrict__ Ss, const int* __restrict__ offsets,
    const int* __restrict__ srcSorted, float* __restrict__ AggS)
{
  int idx = blockIdx.x * 256 + threadIdx.x;
  int node = idx >> 3, c = idx & 7;
  if (node >= N_NODES) return;
  int b = offsets[node], e = offsets[node + 1];
  float s = 0.f;
  for (int p = b; p < e; ++p) s += Ss[(size_t)srcSorted[p] * 8 + c];
  AggS[idx] = s;
}

// ---------------- Xp[g,c,h] = sum_{n in g} Ss[n,c] * Z[n,h] ----------------
__global__ __launch_bounds__(256) void xp_kernel(
    const float* __restrict__ Ss, const float* __restrict__ Z,
    float* __restrict__ Xp)
{
  const int g = blockIdx.x >> 3;
  const int chunk = blockIdx.x & 7;
  const int t = threadIdx.x;
  const int n0 = g * NPG + chunk * 125;
  __shared__ float ls[32 * 8];
  float acc[8];
#pragma unroll
  for (int c = 0; c < 8; ++c) acc[c] = 0.f;
  for (int c0 = 0; c0 < 125; c0 += 32) {
    int cc = min(32, 125 - c0);
    __syncthreads();
    if (t < cc * 8) ls[t] = Ss[(size_t)(n0 + c0) * 8 + t];
    __syncthreads();
    for (int i = 0; i < cc; ++i) {
      float zv = Z[(size_t)(n0 + c0 + i) * 256 + t];
#pragma unroll
      for (int c = 0; c < 8; ++c) acc[c] = fmaf(ls[i * 8 + c], zv, acc[c]);
    }
  }
#pragma unroll
  for (int c = 0; c < 8; ++c)
    atomicAdd(&Xp[((size_t)g * 8 + c) * 256 + t], acc[c]);
}

// ---------------- Ap[g,i,j] += sum_{n in chunk} AggS[n,i] * Ss[n,j] ----------------
__global__ __launch_bounds__(64) void ap_kernel(
    const float* __restrict__ AggS, const float* __restrict__ Ss,
    float* __restrict__ Ap)
{
  const int g = blockIdx.x >> 3;
  const int chunk = blockIdx.x & 7;
  const int t = threadIdx.x;
  const int i = t >> 3, j = t & 7;
  __shared__ float lA[64 * 8], lS[64 * 8];
  float acc = 0.f;
  const int base = g * NPG + chunk * 125;
  for (int c0 = 0; c0 < 125; c0 += 64) {
    int cc = min(64, 125 - c0);
    __syncthreads();
    if (t < cc) {
      const float4* pa = (const float4*)(AggS + (size_t)(base + c0 + t) * 8);
      *(float4*)&lA[t * 8]     = pa[0];
      *(float4*)&lA[t * 8 + 4] = pa[1];
      const float4* ps = (const float4*)(Ss + (size_t)(base + c0 + t) * 8);
      *(float4*)&lS[t * 8]     = ps[0];
      *(float4*)&lS[t * 8 + 4] = ps[1];
    }
    __syncthreads();
    for (int n = 0; n < cc; ++n) acc = fmaf(lA[n * 8 + i], lS[n * 8 + j], acc);
  }
  atomicAdd(&Ap[(size_t)g * 64 + t], acc);
}

// ---------------- final: mask/deg -> agg -> Zp -> classifier -> out[g] ----------------
// 1024 threads: c = t&255 (channel), q = t>>8 (k-split / j-split).
__global__ __launch_bounds__(1024) void final_kernel(
    const float* __restrict__ Xp, const float* __restrict__ Ap,
    const float* __restrict__ Wl2, const float* __restrict__ bl2,
    const float* __restrict__ Wr2, const float* __restrict__ Wc1,
    const float* __restrict__ bc1, const float* __restrict__ Wc2,
    const float* __restrict__ bc2, float* __restrict__ out)
{
  const int g = blockIdx.x;
  const int t = threadIdx.x;
  const int c = t & 255, q = t >> 8;
  __shared__ float lAp[64];
  __shared__ float lXp[8][256];
  __shared__ float lAgg[8][256];
  __shared__ float lG[2048];
  __shared__ float part[4][256];
  __shared__ float red[256];
  if (t < 64) lAp[t] = Ap[g * 64 + t];
  lXp[q][c]     = Xp[((size_t)g * 8 + q) * 256 + c];
  lXp[q + 4][c] = Xp[((size_t)g * 8 + q + 4) * 256 + c];
  __syncthreads();
#pragma unroll
  for (int jj = 0; jj < 2; ++jj) {
    int j = q + jj * 4;
    float d = 0.f, s = 0.f;
#pragma unroll
    for (int i = 0; i < 8; ++i) {
      bool m = (lAp[i * 8 + j] != 0.f);
      d += m ? 1.f : 0.f;
      s += m ? lXp[i][c] : 0.f;
    }
    lAgg[j][c] = (d > 0.f) ? s / fmaxf(d, 1.f) : 0.f;
  }
  __syncthreads();
#pragma unroll
  for (int jj = 0; jj < 2; ++jj) {
    int j = q + jj * 4;
    float az = bl2[c];
#pragma unroll 4
    for (int k = 0; k < 256; ++k) {
      az += lAgg[j][k] * Wl2[(size_t)k * 256 + c] + lXp[j][k] * Wr2[(size_t)k * 256 + c];
    }
    lG[j * 256 + c] = fmaxf(az, 0.f);
  }
  __syncthreads();
  float a = 0.f;
  const int kb = q * 512;
#pragma unroll 4
  for (int k = kb; k < kb + 512; ++k) a = fmaf(lG[k], Wc1[(size_t)k * 256 + c], a);
  part[q][c] = a;
  __syncthreads();
  if (t < 256) {
    float s = bc1[t] + part[0][t] + part[1][t] + part[2][t] + part[3][t];
    red[t] = fmaxf(s, 0.f) * Wc2[t];
  }
  __syncthreads();
  for (int off = 128; off > 0; off >>= 1) {
    if (t < off) red[t] += red[t + off];
    __syncthreads();
  }
  if (t == 0) out[g] = red[0] + bc2[0];
}

extern "C" void kernel_launch(void* const* d_in, const int* in_sizes, int n_in,
                              void* d_out, int out_size, void* d_ws, size_t ws_size,
                              hipStream_t stream) {
  const float* x   = (const float*)d_in[0];
  const int*   ei  = (const int*)d_in[1];
  const float* Wl1 = (const float*)d_in[3];
  const float* bl1 = (const float*)d_in[4];
  const float* Wr1 = (const float*)d_in[5];
  const float* Wla = (const float*)d_in[6];
  const float* bla = (const float*)d_in[7];
  const float* Wra = (const float*)d_in[8];
  const float* Wl2 = (const float*)d_in[9];
  const float* bl2 = (const float*)d_in[10];
  const float* Wr2 = (const float*)d_in[11];
  const float* Wc1 = (const float*)d_in[12];
  const float* bc1 = (const float*)d_in[13];
  const float* Wc2 = (const float*)d_in[14];
  const float* bc2 = (const float*)d_in[15];
  float* out = (float*)d_out;

  // workspace layout (~72 MB)
  _Float16* C   = (_Float16*)d_ws;              // 32000*512 fp16
  _Float16* WsT = C + 32000 * 512;              // 512*1024 fp16
  float* SP   = (float*)(WsT + 512 * 1024);     // 32000*16
  float* Z    = SP + 512000;                    // 32000*256
  float* Ss   = Z + 8192000;                    // 32000*8
  float* AggS = Ss + 256000;                    // 32000*8
  float* Xp   = AggS + 256000;                  // 32*8*256
  float* Ap   = Xp + 65536;                     // 32*64
  int* deg     = (int*)(Ap + 2048);             // 32000
  int* cursor  = deg + 32000;                   // 32000
  int* offsets = cursor + 32000;                // 32001
  int* srcS    = offsets + 32001;               // 256000

  const int* src = ei;
  const int* dst = ei + N_EDGES;

  fill_zero_u32<<<(64000 + 255) / 256, 256, 0, stream>>>((unsigned*)deg, 64000);
  fill_zero_u32<<<(65536 + 2048 + 255) / 256, 256, 0, stream>>>((unsigned*)Xp, 65536 + 2048);

  convert_w<<<dim3(32, 16), 256, 0, stream>>>(Wl1, Wr1, WsT);
  gemm_mfma<<<1000, 256, 0, stream>>>(x, WsT, C);
  skinny16<<<4000, 256, 0, stream>>>(x, Wla, Wra, SP);

  count_deg<<<1000, 256, 0, stream>>>(dst, deg);
  scan_kernel<<<1, 1024, 0, stream>>>(deg, offsets);
  scatter_kernel<<<1000, 256, 0, stream>>>(src, dst, offsets, cursor, srcS);

  aggregate_node<<<32000, 256, 0, stream>>>(C, SP, offsets, srcS, bl1, bla, Z, Ss);
  agg_ss<<<1000, 256, 0, stream>>>(Ss, offsets, srcS, AggS);
  xp_kernel<<<256, 256, 0, stream>>>(Ss, Z, Xp);
  ap_kernel<<<256, 64, 0, stream>>>(AggS, Ss, Ap);
  final_kernel<<<32, 1024, 0, stream>>>(Xp, Ap, Wl2, bl2, Wr2, Wc1, bc1, Wc2, bc2, out);
}

// Round 4
// 320.432 us; speedup vs baseline: 2.8909x; 1.4501x over previous
//
#include <hip/hip_runtime.h>
#include <hip/hip_bf16.h>
#include <math.h>

#define N_NODES 32000
#define NUM_GRAPHS 32
#define NPG 1000
#define N_EDGES 256000
#define IN_DIM 1024
#define HID 256
#define NW 528   // C width: 256 (Wl1) + 256 (Wr1) + 8 (Wla) + 8 (Wra)
#define KBS 1040 // LDS stride per k-block: 128*8 + 16 pad halves (2080 B -> bank offset 8/kb)

typedef _Float16 half8 __attribute__((ext_vector_type(8)));
typedef float f32x4 __attribute__((ext_vector_type(4)));

__device__ __forceinline__ void gload16(const void* g, void* l) {
  __builtin_amdgcn_global_load_lds((const __attribute__((address_space(1))) void*)g,
                                   (__attribute__((address_space(3))) void*)l, 16, 0, 0);
}

// ---------------- prep: zero scratch counters + build tiled fp16 weight buffer ----------------
// WsT2 layout per K-step (32 k): nb<4 chunks at nb*4096 + c*8 (c = kb*128 + nl);
// SP cols at 16384 + (kb*16 + ns)*8. 16896 halves per K-step.
__global__ __launch_bounds__(256) void prep_kernel(
    const float* __restrict__ Wl1, const float* __restrict__ Wr1,
    const float* __restrict__ Wla, const float* __restrict__ Wra,
    _Float16* __restrict__ WsT2, unsigned* __restrict__ zbuf)
{
  const int t = threadIdx.x;
  const int flat = blockIdx.y * 3 + blockIdx.x;   // 0..383
  for (int i = flat * 256 + t; i < 131584; i += 384 * 256) zbuf[i] = 0u;

  const int kslot = blockIdx.y;        // 0..127 -> k0 = kslot*8
  const int n = blockIdx.x * 256 + t;
  if (n >= NW) return;
  const int k0 = kslot * 8;
  half8 o;
#pragma unroll
  for (int i = 0; i < 8; ++i) {
    const int k = k0 + i;
    float v;
    if (n < 256)      v = Wl1[(size_t)k * 256 + n];
    else if (n < 512) v = Wr1[(size_t)k * 256 + n - 256];
    else if (n < 520) v = Wla[(size_t)k * 8 + n - 512];
    else              v = Wra[(size_t)k * 8 + n - 520];
    o[i] = (_Float16)v;
  }
  const int K = kslot >> 2, kb = kslot & 3;
  size_t off;
  if (n < 512) off = (size_t)K * 16896 + (size_t)(n >> 7) * 4096 + kb * 1024 + (n & 127) * 8;
  else         off = (size_t)K * 16896 + 16384 + kb * 128 + (n - 512) * 8;
  *(half8*)&WsT2[off] = o;
}

// ---------------- MFMA GEMM: C[32000,528](fp16) = x @ [Wl1|Wr1|Wla|Wra], split-fp16 ----------------
// 1250 blocks = 250 m-panels x 5 nb (nb 0..3: BN=128; nb 4: BN=16).
// LDS sub-tiled [kb](stride KBS)[row][8]: quarter-wave reads 256B contiguous,
// kb groups offset by 8 banks -> conflict-free ds_read_b128.
__global__ __launch_bounds__(256) void gemm_mfma(
    const float* __restrict__ x, const _Float16* __restrict__ WsT2,
    _Float16* __restrict__ C)
{
  const int orig = blockIdx.x;
  const int xcd = orig & 7, idx = orig >> 3;
  // bijective XCD swizzle, nwg=1250: q=156, r=2
  const int g = (xcd < 2 ? xcd * 157 : 314 + (xcd - 2) * 156) + idx;
  const int pm = g / 5, nb = g % 5;
  const int m0 = pm * 128;

  __shared__ _Float16 AH[4 * KBS];
  __shared__ _Float16 AL[4 * KBS];
  __shared__ _Float16 Bs[4 * KBS];

  const int tid = threadIdx.x;
  const int w = tid >> 6, l = tid & 63;
  const int wr = w >> 1, wc = w & 1;
  const int r16 = l & 15, kb4 = l >> 4;

  const int arow = tid >> 1, akc = (tid & 1) << 4;
  const float* aptr = x + (size_t)(m0 + arow) * IN_DIM + akc;
  const int kbw = akc >> 3;   // 0 or 2
  _Float16* ah0 = &AH[kbw * KBS + arow * 8];
  _Float16* ah1 = &AH[(kbw + 1) * KBS + arow * 8];
  _Float16* al0 = &AL[kbw * KBS + arow * 8];
  _Float16* al1 = &AL[(kbw + 1) * KBS + arow * 8];

  if (nb < 4) {
    const _Float16* bg0 = WsT2 + nb * 4096 + tid * 8;
    const _Float16* bg1 = WsT2 + nb * 4096 + (tid + 256) * 8;
    _Float16* bl0 = &Bs[(tid >> 7) * KBS + (tid & 127) * 8];
    _Float16* bl1 = &Bs[(2 + (tid >> 7)) * KBS + (tid & 127) * 8];

    f32x4 acc[4][4] = {};
    for (int ks = 0; ks < 32; ++ks) {
      float av[16];
      *(float4*)&av[0]  = *(const float4*)(aptr + ks * 32);
      *(float4*)&av[4]  = *(const float4*)(aptr + ks * 32 + 4);
      *(float4*)&av[8]  = *(const float4*)(aptr + ks * 32 + 8);
      *(float4*)&av[12] = *(const float4*)(aptr + ks * 32 + 12);
      __syncthreads();
      gload16(bg0 + (size_t)ks * 16896, bl0);
      gload16(bg1 + (size_t)ks * 16896, bl1);
      half8 hh[2], hl[2];
#pragma unroll
      for (int i = 0; i < 16; ++i) {
        _Float16 h = (_Float16)av[i];
        ((_Float16*)hh)[i] = h;
        ((_Float16*)hl)[i] = (_Float16)(av[i] - (float)h);
      }
      *(half8*)ah0 = hh[0];
      *(half8*)ah1 = hh[1];
      *(half8*)al0 = hl[0];
      *(half8*)al1 = hl[1];
      __syncthreads();

      half8 bf[4];
#pragma unroll
      for (int n = 0; n < 4; ++n)
        bf[n] = *(half8*)&Bs[kb4 * KBS + (wc * 64 + n * 16 + r16) * 8];
#pragma unroll
      for (int m = 0; m < 4; ++m) {
        half8 ah = *(half8*)&AH[kb4 * KBS + (wr * 64 + m * 16 + r16) * 8];
        half8 al = *(half8*)&AL[kb4 * KBS + (wr * 64 + m * 16 + r16) * 8];
#pragma unroll
        for (int n = 0; n < 4; ++n) {
          acc[m][n] = __builtin_amdgcn_mfma_f32_16x16x32_f16(ah, bf[n], acc[m][n], 0, 0, 0);
          acc[m][n] = __builtin_amdgcn_mfma_f32_16x16x32_f16(al, bf[n], acc[m][n], 0, 0, 0);
        }
      }
    }
    const int crow0 = m0 + wr * 64 + ((l >> 4) << 2);
    const int ccol0 = nb * 128 + wc * 64 + r16;
#pragma unroll
    for (int m = 0; m < 4; ++m)
#pragma unroll
      for (int n = 0; n < 4; ++n)
#pragma unroll
        for (int r = 0; r < 4; ++r)
          C[(size_t)(crow0 + m * 16 + r) * NW + ccol0 + n * 16] = (_Float16)acc[m][n][r];
  } else {
    // SP block: 16 output cols (512..527); 512 halves = 64 x 16B chunks -> tid<64
    const _Float16* bg0 = WsT2 + 16384 + tid * 8;
    _Float16* bl0 = &Bs[tid * 8];   // linear (wave 0 only)

    f32x4 acc2[2] = {};
    for (int ks = 0; ks < 32; ++ks) {
      float av[16];
      *(float4*)&av[0]  = *(const float4*)(aptr + ks * 32);
      *(float4*)&av[4]  = *(const float4*)(aptr + ks * 32 + 4);
      *(float4*)&av[8]  = *(const float4*)(aptr + ks * 32 + 8);
      *(float4*)&av[12] = *(const float4*)(aptr + ks * 32 + 12);
      __syncthreads();
      if (tid < 64) gload16(bg0 + (size_t)ks * 16896, bl0);
      half8 hh[2], hl[2];
#pragma unroll
      for (int i = 0; i < 16; ++i) {
        _Float16 h = (_Float16)av[i];
        ((_Float16*)hh)[i] = h;
        ((_Float16*)hl)[i] = (_Float16)(av[i] - (float)h);
      }
      *(half8*)ah0 = hh[0];
      *(half8*)ah1 = hh[1];
      *(half8*)al0 = hl[0];
      *(half8*)al1 = hl[1];
      __syncthreads();

      half8 bf = *(half8*)&Bs[(kb4 * 16 + r16) * 8];
#pragma unroll
      for (int m = 0; m < 2; ++m) {
        half8 ah = *(half8*)&AH[kb4 * KBS + (w * 32 + m * 16 + r16) * 8];
        half8 al = *(half8*)&AL[kb4 * KBS + (w * 32 + m * 16 + r16) * 8];
        acc2[m] = __builtin_amdgcn_mfma_f32_16x16x32_f16(ah, bf, acc2[m], 0, 0, 0);
        acc2[m] = __builtin_amdgcn_mfma_f32_16x16x32_f16(al, bf, acc2[m], 0, 0, 0);
      }
    }
    const int crow0 = m0 + w * 32 + ((l >> 4) << 2);
    const int ccol0 = 512 + r16;
#pragma unroll
    for (int m = 0; m < 2; ++m)
#pragma unroll
      for (int r = 0; r < 4; ++r)
        C[(size_t)(crow0 + m * 16 + r) * NW + ccol0] = (_Float16)acc2[m][r];
  }
}

// ---------------- CSR build ----------------
__global__ void count_deg(const int* __restrict__ dst, int* __restrict__ deg) {
  int e = blockIdx.x * blockDim.x + threadIdx.x;
  if (e < N_EDGES) atomicAdd(&deg[dst[e]], 1);
}

__global__ __launch_bounds__(1024) void scan_kernel(const int* __restrict__ deg,
                                                    int* __restrict__ offsets) {
  __shared__ int part[1024];
  const int t = threadIdx.x;
  const int base = t * 32;
  int vals[32];
  if (t < 1000) {
#pragma unroll
    for (int j = 0; j < 8; ++j) {
      int4 v = *(const int4*)(deg + base + j * 4);
      vals[j * 4 + 0] = v.x; vals[j * 4 + 1] = v.y;
      vals[j * 4 + 2] = v.z; vals[j * 4 + 3] = v.w;
    }
  } else {
#pragma unroll
    for (int i = 0; i < 32; ++i) vals[i] = 0;
  }
  int local[32];
  int s = 0;
#pragma unroll
  for (int i = 0; i < 32; ++i) { local[i] = s; s += vals[i]; }
  part[t] = s;
  __syncthreads();
  for (int off = 1; off < 1024; off <<= 1) {
    int v = (t >= off) ? part[t - off] : 0;
    __syncthreads();
    part[t] += v;
    __syncthreads();
  }
  int excl = part[t] - s;
  if (t < 1000) {
#pragma unroll
    for (int i = 0; i < 32; ++i) offsets[base + i] = excl + local[i];
  }
  if (t == 1023) offsets[N_NODES] = part[1023];
}

__global__ void scatter_kernel(const int* __restrict__ src, const int* __restrict__ dst,
                               const int* __restrict__ offsets, int* __restrict__ cursor,
                               int* __restrict__ srcSorted) {
  int e = blockIdx.x * blockDim.x + threadIdx.x;
  if (e < N_EDGES) {
    int d = dst[e];
    int pos = offsets[d] + atomicAdd(&cursor[d], 1);
    srcSorted[pos] = src[e];
  }
}

// ---------------- per-node aggregation: Z + Ss from C ----------------
__global__ __launch_bounds__(256) void aggregate_node(
    const _Float16* __restrict__ C,
    const int* __restrict__ offsets, const int* __restrict__ srcSorted,
    const float* __restrict__ bl1, const float* __restrict__ bla,
    float* __restrict__ Z, float* __restrict__ Ss)
{
  const int bid = blockIdx.x;
  const int node = (bid & 7) * 4000 + (bid >> 3);   // graphs pinned to XCDs
  const int t = threadIdx.x;
  const int b = offsets[node], e = offsets[node + 1];
  const int cnt = e - b;
  float accP = 0.f;
  for (int p = b; p < e; ++p) {
    int s = srcSorted[p];
    accP += (float)C[(size_t)s * NW + t];
  }
  const float inv = (cnt > 0) ? 1.f / (float)cnt : 0.f;
  float z = accP * inv + bl1[t] + (float)C[(size_t)node * NW + 256 + t];
  Z[(size_t)node * 256 + t] = fmaxf(z, 0.f);

  __shared__ float sS[8];
  if (t < 8) {
    float a = 0.f;
    for (int p = b; p < e; ++p) a += (float)C[(size_t)srcSorted[p] * NW + 512 + t];
    sS[t] = a * inv + bla[t] + (float)C[(size_t)node * NW + 520 + t];
  }
  __syncthreads();
  if (t < 8) {
    float m = sS[0];
#pragma unroll
    for (int c = 1; c < 8; ++c) m = fmaxf(m, sS[c]);
    float denom = 0.f;
#pragma unroll
    for (int c = 0; c < 8; ++c) denom += expf(sS[c] - m);
    Ss[(size_t)node * 8 + t] = expf(sS[t] - m) / denom;
  }
}

// ---------------- pool: per 125-node chunk: AggS (LDS) -> Ap partial + Xp partial ----------------
__global__ __launch_bounds__(256) void pool_kernel(
    const float* __restrict__ Ss, const float* __restrict__ Z,
    const int* __restrict__ offsets, const int* __restrict__ srcSorted,
    float* __restrict__ Xp, float* __restrict__ Ap)
{
  const int g = blockIdx.x >> 3;
  const int chunk = blockIdx.x & 7;
  const int n0 = g * NPG + chunk * 125;
  const int t = threadIdx.x;
  __shared__ float lSs[125][8];
  __shared__ float lAg[125][8];
  __shared__ float apTmp[4][64];

  if (t < 125) {
    const int node = n0 + t;
    float4 s0 = *(const float4*)&Ss[(size_t)node * 8];
    float4 s1 = *(const float4*)&Ss[(size_t)node * 8 + 4];
    lSs[t][0] = s0.x; lSs[t][1] = s0.y; lSs[t][2] = s0.z; lSs[t][3] = s0.w;
    lSs[t][4] = s1.x; lSs[t][5] = s1.y; lSs[t][6] = s1.z; lSs[t][7] = s1.w;
    float a[8] = {0.f, 0.f, 0.f, 0.f, 0.f, 0.f, 0.f, 0.f};
    const int b = offsets[node], e = offsets[node + 1];
    for (int p = b; p < e; ++p) {
      const int s = srcSorted[p];
      float4 v0 = *(const float4*)&Ss[(size_t)s * 8];
      float4 v1 = *(const float4*)&Ss[(size_t)s * 8 + 4];
      a[0] += v0.x; a[1] += v0.y; a[2] += v0.z; a[3] += v0.w;
      a[4] += v1.x; a[5] += v1.y; a[6] += v1.z; a[7] += v1.w;
    }
#pragma unroll
    for (int c = 0; c < 8; ++c) lAg[t][c] = a[c];
  }
  __syncthreads();
  // Ap partial: Ap[g,i,j] += sum_n lAg[n][i] * lSs[n][j]
  {
    const int sl = t >> 6, i = (t >> 3) & 7, j = t & 7;
    float acc = 0.f;
    for (int n = sl; n < 125; n += 4) acc += lAg[n][i] * lSs[n][j];
    apTmp[sl][((i << 3) | j)] = acc;
  }
  __syncthreads();
  if (t < 64) atomicAdd(&Ap[g * 64 + t], apTmp[0][t] + apTmp[1][t] + apTmp[2][t] + apTmp[3][t]);
  // Xp partial: Xp[g,c,h] += sum_n lSs[n][c] * Z[n][h]
  float xc[8] = {0.f, 0.f, 0.f, 0.f, 0.f, 0.f, 0.f, 0.f};
  for (int n = 0; n < 125; ++n) {
    float zv = Z[(size_t)(n0 + n) * 256 + t];
#pragma unroll
    for (int c = 0; c < 8; ++c) xc[c] = fmaf(lSs[n][c], zv, xc[c]);
  }
#pragma unroll
  for (int c = 0; c < 8; ++c)
    atomicAdd(&Xp[((size_t)g * 8 + c) * 256 + t], xc[c]);
}

// ---------------- final: mask/deg -> agg -> Zp -> classifier -> out[g] ----------------
__global__ __launch_bounds__(1024) void final_kernel(
    const float* __restrict__ Xp, const float* __restrict__ Ap,
    const float* __restrict__ Wl2, const float* __restrict__ bl2,
    const float* __restrict__ Wr2, const float* __restrict__ Wc1,
    const float* __restrict__ bc1, const float* __restrict__ Wc2,
    const float* __restrict__ bc2, float* __restrict__ out)
{
  const int g = blockIdx.x;
  const int t = threadIdx.x;
  const int c = t & 255, q = t >> 8;
  __shared__ float lAp[64];
  __shared__ float lXp[8][256];
  __shared__ float lAgg[8][256];
  __shared__ float lG[2048];
  __shared__ float part[4][256];
  __shared__ float red[256];
  if (t < 64) lAp[t] = Ap[g * 64 + t];
  lXp[q][c]     = Xp[((size_t)g * 8 + q) * 256 + c];
  lXp[q + 4][c] = Xp[((size_t)g * 8 + q + 4) * 256 + c];
  __syncthreads();
#pragma unroll
  for (int jj = 0; jj < 2; ++jj) {
    int j = q + jj * 4;
    float d = 0.f, s = 0.f;
#pragma unroll
    for (int i = 0; i < 8; ++i) {
      bool m = (lAp[i * 8 + j] != 0.f);
      d += m ? 1.f : 0.f;
      s += m ? lXp[i][c] : 0.f;
    }
    lAgg[j][c] = (d > 0.f) ? s / fmaxf(d, 1.f) : 0.f;
  }
  __syncthreads();
#pragma unroll
  for (int jj = 0; jj < 2; ++jj) {
    int j = q + jj * 4;
    float az = bl2[c];
#pragma unroll 4
    for (int k = 0; k < 256; ++k) {
      az += lAgg[j][k] * Wl2[(size_t)k * 256 + c] + lXp[j][k] * Wr2[(size_t)k * 256 + c];
    }
    lG[j * 256 + c] = fmaxf(az, 0.f);
  }
  __syncthreads();
  float a = 0.f;
  const int kb = q * 512;
#pragma unroll 4
  for (int k = kb; k < kb + 512; ++k) a = fmaf(lG[k], Wc1[(size_t)k * 256 + c], a);
  part[q][c] = a;
  __syncthreads();
  if (t < 256) {
    float s = bc1[t] + part[0][t] + part[1][t] + part[2][t] + part[3][t];
    red[t] = fmaxf(s, 0.f) * Wc2[t];
  }
  __syncthreads();
  for (int off = 128; off > 0; off >>= 1) {
    if (t < off) red[t] += red[t + off];
    __syncthreads();
  }
  if (t == 0) out[g] = red[0] + bc2[0];
}

extern "C" void kernel_launch(void* const* d_in, const int* in_sizes, int n_in,
                              void* d_out, int out_size, void* d_ws, size_t ws_size,
                              hipStream_t stream) {
  const float* x   = (const float*)d_in[0];
  const int*   ei  = (const int*)d_in[1];
  const float* Wl1 = (const float*)d_in[3];
  const float* bl1 = (const float*)d_in[4];
  const float* Wr1 = (const float*)d_in[5];
  const float* Wla = (const float*)d_in[6];
  const float* bla = (const float*)d_in[7];
  const float* Wra = (const float*)d_in[8];
  const float* Wl2 = (const float*)d_in[9];
  const float* bl2 = (const float*)d_in[10];
  const float* Wr2 = (const float*)d_in[11];
  const float* Wc1 = (const float*)d_in[12];
  const float* bc1 = (const float*)d_in[13];
  const float* Wc2 = (const float*)d_in[14];
  const float* bc2 = (const float*)d_in[15];
  float* out = (float*)d_out;

  // workspace layout (~70 MB)
  _Float16* C    = (_Float16*)d_ws;                 // 32000*528
  _Float16* WsT2 = C + (size_t)32000 * NW;          // 540672
  float* Z    = (float*)(WsT2 + 540672);            // 32000*256
  float* Ss   = Z + 8192000;                        // 32000*8
  float* Xp   = Ss + 256000;                        // 32*8*256
  float* Ap   = Xp + 65536;                         // 32*64
  int* deg     = (int*)(Ap + 2048);                 // 32000
  int* cursor  = deg + 32000;                       // 32000
  int* offsets = cursor + 32000;                    // 32001
  int* srcS    = offsets + 32001;                   // 256000
  unsigned* zbuf = (unsigned*)Xp;                   // Xp+Ap+deg+cursor = 131584 words

  const int* src = ei;
  const int* dst = ei + N_EDGES;

  prep_kernel<<<dim3(3, 128), 256, 0, stream>>>(Wl1, Wr1, Wla, Wra, WsT2, zbuf);
  count_deg<<<1000, 256, 0, stream>>>(dst, deg);
  scan_kernel<<<1, 1024, 0, stream>>>(deg, offsets);
  scatter_kernel<<<1000, 256, 0, stream>>>(src, dst, offsets, cursor, srcS);
  gemm_mfma<<<1250, 256, 0, stream>>>(x, WsT2, C);
  aggregate_node<<<32000, 256, 0, stream>>>(C, offsets, srcS, bl1, bla, Z, Ss);
  pool_kernel<<<256, 256, 0, stream>>>(Ss, Z, offsets, srcS, Xp, Ap);
  final_kernel<<<32, 1024, 0, stream>>>(Xp, Ap, Wl2, bl2, Wr2, Wc1, bc1, Wc2, bc2, out);
}